// Round 2
// baseline (307.694 us; speedup 1.0000x reference)
//
#include <hip/hip_runtime.h>
#include <hip/hip_bf16.h>

#define N_IMG 32
#define CIN   128
#define INH   64
#define INW   64
#define COUT  256
#define OH    62
#define OW    62

typedef short          bf16x8 __attribute__((ext_vector_type(8)));
typedef unsigned short u16x8  __attribute__((ext_vector_type(8)));
typedef float          f32x4  __attribute__((ext_vector_type(4)));
typedef float          f32x16 __attribute__((ext_vector_type(16)));

__device__ __forceinline__ unsigned short f2bf(float x) {
    unsigned int u = __float_as_uint(x);
    u += 0x7fffu + ((u >> 16) & 1u);   // RNE
    return (unsigned short)(u >> 16);
}

// async global->LDS, 16B per lane; LDS dest = uniform base + lane*16
__device__ __forceinline__ void gl2lds16(const unsigned short* g, unsigned short* l) {
    __builtin_amdgcn_global_load_lds(
        (const __attribute__((address_space(1))) unsigned int*)g,
        (__attribute__((address_space(3))) unsigned int*)l,
        16, 0, 0);
}

// WT layout: [khw(9)][cg(16)][co(256)][i(8)] bf16, ci = cg*8 + i.
// Serves both 16x16x32 (cg = cb*4 + q) and 32x32x16 (cg = cb*4 + kc*2 + h) A-frags.
__global__ void wt_transform_kernel(const float* __restrict__ Wsrc,
                                    unsigned short* __restrict__ WT) {
    int idx = blockIdx.x * 256 + threadIdx.x;          // < 294912
    int i   = idx & 7;
    int co  = (idx >> 3) & 255;
    int cgk = idx >> 11;
    int cg  = cgk & 15;
    int khw = cgk >> 4;
    int kh  = khw / 3, kw = khw - 3 * kh;
    int ci  = cg * 8 + i;
    WT[idx] = f2bf(Wsrc[co * (CIN * 9) + ci * 9 + kh * 3 + kw]);
}

// Input pre-pass: f32 NCHW -> bf16 InT[img][ih][iw][ci], with the 16B ci-chunk
// (8 ci) stored at position (ci>>3) ^ (iw & 15)  -> bank-uniform ds_read_b128.
__global__ void in_transform_kernel(const float* __restrict__ In,
                                    unsigned short* __restrict__ InT) {
    const int ih  = blockIdx.x & 63;
    const int img = blockIdx.x >> 6;
    const int t   = threadIdx.x;
    const int iw  = t & 63;
    const int cg  = t >> 6;                 // 0..3 -> 32-ci group
    const float* ip = In + (((size_t)img * CIN) * INH + ih) * INW + iw;
    unsigned short* op = InT + (((size_t)(img * INH + ih) * INW) + iw) * CIN;
#pragma unroll
    for (int cc = 0; cc < 4; ++cc) {
        const int cf = cg * 4 + cc;         // chunk index 0..15
        u16x8 v;
#pragma unroll
        for (int j = 0; j < 8; ++j)
            v[j] = f2bf(ip[(size_t)(cf * 8 + j) * (INH * INW)]);
        *(u16x8*)(op + ((cf ^ (iw & 15)) * 8)) = v;
    }
}

// Main conv: one block per (img, oh-pair). Wave w: co in [64w,64w+64).
// Single staging phase (4 rows x 64 iw x 128 ci bf16 = 64KB LDS via
// global_load_lds), ONE barrier, then 4cb x 9taps x 16 MFMA(32x32x16).
__global__ __launch_bounds__(256, 2)
void conv_mfma32_kernel(const unsigned short* __restrict__ InT,
                        const unsigned short* __restrict__ WT,
                        float* __restrict__ Out) {
    __shared__ __align__(16) unsigned short Lin[258 * CIN];  // 4 rows*64iw + guard

    const int oh0  = blockIdx.x * 2;
    const int img  = blockIdx.y;
    const int tid  = threadIdx.x;
    const int wave = tid >> 6;
    const int lane = tid & 63;
    const int h    = lane >> 5;      // k-half
    const int m32  = lane & 31;
    const int co_base = wave * 64;

    // ---- stage: wave w copies row ih = oh0 + w (16 KB contiguous) ----
    {
        const unsigned short* src =
            InT + ((size_t)(img * INH + (oh0 + wave)) * INW) * CIN;
        unsigned short* dst = Lin + wave * (INW * CIN);
#pragma unroll
        for (int i = 0; i < 16; ++i)
            gl2lds16(src + i * 512 + lane * 8, dst + i * 512);
    }
    __syncthreads();

    f32x16 acc[2][2][2];   // [oh][mi][ni]
#pragma unroll
    for (int a = 0; a < 2; ++a)
#pragma unroll
        for (int b = 0; b < 2; ++b)
#pragma unroll
            for (int c = 0; c < 2; ++c)
#pragma unroll
                for (int g = 0; g < 16; ++g) acc[a][b][c][g] = 0.f;

    const bf16x8* WTv = (const bf16x8*)WT;

    for (int cb = 0; cb < 4; ++cb) {
#pragma unroll
        for (int kh = 0; kh < 3; ++kh) {
#pragma unroll
            for (int kw = 0; kw < 3; ++kw) {
                const int khw = kh * 3 + kw;
                bf16x8 wf[2][2];   // [mi][kc]
#pragma unroll
                for (int mi = 0; mi < 2; ++mi)
#pragma unroll
                    for (int kc = 0; kc < 2; ++kc)
                        wf[mi][kc] = WTv[(khw * 16 + cb * 4 + kc * 2 + h) * 256 +
                                         co_base + mi * 32 + m32];
                bf16x8 xf[2][2][2];  // [oh][ni][kc]
#pragma unroll
                for (int oi = 0; oi < 2; ++oi) {
                    const int r = oi + kh;
#pragma unroll
                    for (int ni = 0; ni < 2; ++ni) {
                        const int iw = ni * 32 + m32 + kw;
                        const unsigned short* rp = Lin + (r * 64 + iw) * CIN;
#pragma unroll
                        for (int kc = 0; kc < 2; ++kc) {
                            const int cf = cb * 4 + kc * 2 + h;
                            xf[oi][ni][kc] =
                                *(const bf16x8*)(rp + ((cf ^ (iw & 15)) * 8));
                        }
                    }
                }
#pragma unroll
                for (int oi = 0; oi < 2; ++oi)
#pragma unroll
                    for (int mi = 0; mi < 2; ++mi)
#pragma unroll
                        for (int ni = 0; ni < 2; ++ni)
#pragma unroll
                            for (int kc = 0; kc < 2; ++kc)
                                acc[oi][mi][ni] = __builtin_amdgcn_mfma_f32_32x32x16_bf16(
                                    wf[mi][kc], xf[oi][ni][kc], acc[oi][mi][ni], 0, 0, 0);
            }
        }
    }

    // ---- epilogue: C/D: col=lane&31, row=(g&3)+8*(g>>2)+4*h (verified) ----
#pragma unroll
    for (int oi = 0; oi < 2; ++oi) {
        const int oh = oh0 + oi;
#pragma unroll
        for (int mi = 0; mi < 2; ++mi) {
#pragma unroll
            for (int g = 0; g < 16; ++g) {
                const int rr = (g & 3) + 8 * (g >> 2) + 4 * h;
                const int co = co_base + mi * 32 + rr;
                float* op = Out + (((size_t)img * COUT + co) * OH + oh) * OW;
#pragma unroll
                for (int ni = 0; ni < 2; ++ni) {
                    const int ow = ni * 32 + m32;
                    if (ow < OW) op[ow] = acc[oi][mi][ni][g];
                }
            }
        }
    }
}

// ---------- fallback 1: round-1 kernel (needs only WT, 590 KB) ----------
__global__ __launch_bounds__(256, 2)
void conv_mfma16_kernel(const float* __restrict__ In,
                        const unsigned short* __restrict__ WT,
                        float* __restrict__ Out) {
    __shared__ unsigned short Lin[66 * 32];
    const int oh   = blockIdx.x;
    const int img  = blockIdx.y;
    const int tid  = threadIdx.x;
    const int wave = tid >> 6;
    const int lane = tid & 63;
    const int q    = lane >> 4;
    const int ml   = lane & 15;
    const int co_base = wave * 64;

    f32x4 acc[4][4];
    const f32x4 zero = {0.f, 0.f, 0.f, 0.f};
#pragma unroll
    for (int a = 0; a < 4; ++a)
#pragma unroll
        for (int b = 0; b < 4; ++b) acc[a][b] = zero;
    if (tid < 32) ((unsigned int*)&Lin[64 * 32])[tid] = 0u;

    const int s_iw = tid & 63;
    const int s_cg = tid >> 6;
    const bf16x8* WTv = (const bf16x8*)WT;

    for (int kh = 0; kh < 3; ++kh) {
        const int ih = oh + kh;
        for (int cb = 0; cb < 4; ++cb) {
            const float* p = In + (((size_t)(img * CIN + cb * 32 + s_cg * 8) * INH + ih) * INW + s_iw);
            u16x8 v;
#pragma unroll
            for (int i = 0; i < 8; ++i) v[i] = f2bf(p[i * (INH * INW)]);
            __syncthreads();
            *(u16x8*)&Lin[s_iw * 32 + ((s_cg ^ (s_iw & 3)) << 3)] = v;
            __syncthreads();
#pragma unroll
            for (int kw = 0; kw < 3; ++kw) {
                const int khw = kh * 3 + kw;
                bf16x8 wf[4], xf[4];
#pragma unroll
                for (int mi = 0; mi < 4; ++mi)
                    wf[mi] = WTv[(khw * 16 + cb * 4 + q) * 256 + co_base + mi * 16 + ml];
#pragma unroll
                for (int ni = 0; ni < 4; ++ni) {
                    const int row = ni * 16 + ml + kw;
                    xf[ni] = *(const bf16x8*)&Lin[row * 32 + ((q ^ (row & 3)) << 3)];
                }
#pragma unroll
                for (int mi = 0; mi < 4; ++mi)
#pragma unroll
                    for (int ni = 0; ni < 4; ++ni)
                        acc[mi][ni] = __builtin_amdgcn_mfma_f32_16x16x32_bf16(
                            wf[mi], xf[ni], acc[mi][ni], 0, 0, 0);
            }
        }
    }
#pragma unroll
    for (int mi = 0; mi < 4; ++mi)
#pragma unroll
        for (int r = 0; r < 4; ++r) {
            const int co = co_base + mi * 16 + q * 4 + r;
            float* op = Out + (((size_t)img * COUT + co) * OH + oh) * OW;
#pragma unroll
            for (int ni = 0; ni < 4; ++ni) {
                const int ow = ni * 16 + ml;
                if (ow < OW) op[ow] = acc[mi][ni][r];
            }
        }
}

// ---------- fallback 2: naive ----------
__global__ void conv_naive_kernel(const float* __restrict__ In,
                                  const float* __restrict__ Wt,
                                  float* __restrict__ Out) {
    int idx = blockIdx.x * 256 + threadIdx.x;
    const int total = N_IMG * COUT * OH * OW;
    if (idx >= total) return;
    int ow = idx % OW; int t = idx / OW;
    int oh = t % OH;   t /= OH;
    int co = t % COUT; int img = t / COUT;
    float s = 0.f;
    for (int ci = 0; ci < CIN; ++ci)
#pragma unroll
        for (int kh = 0; kh < 3; ++kh)
#pragma unroll
            for (int kw = 0; kw < 3; ++kw)
                s += In[((size_t)(img * CIN + ci) * INH + oh + kh) * INW + ow + kw] *
                     Wt[co * CIN * 9 + ci * 9 + kh * 3 + kw];
    Out[idx] = s;
}

extern "C" void kernel_launch(void* const* d_in, const int* in_sizes, int n_in,
                              void* d_out, int out_size, void* d_ws, size_t ws_size,
                              hipStream_t stream) {
    const float* In   = (const float*)d_in[0];
    const float* Wsrc = (const float*)d_in[1];
    float* Out        = (float*)d_out;

    const size_t WT_BYTES  = (size_t)9 * 16 * 256 * 8 * sizeof(unsigned short); // 589824
    const size_t INT_OFF   = 1u << 20;
    const size_t INT_BYTES = (size_t)N_IMG * INH * INW * CIN * sizeof(unsigned short); // 33.5MB

    if (ws_size >= INT_OFF + INT_BYTES) {
        unsigned short* WT  = (unsigned short*)d_ws;
        unsigned short* InT = (unsigned short*)((char*)d_ws + INT_OFF);
        wt_transform_kernel<<<dim3(294912 / 256), dim3(256), 0, stream>>>(Wsrc, WT);
        in_transform_kernel<<<dim3(N_IMG * INH), dim3(256), 0, stream>>>(In, InT);
        conv_mfma32_kernel<<<dim3(OH / 2, N_IMG), dim3(256), 0, stream>>>(InT, WT, Out);
    } else if (ws_size >= WT_BYTES) {
        unsigned short* WT = (unsigned short*)d_ws;
        wt_transform_kernel<<<dim3(294912 / 256), dim3(256), 0, stream>>>(Wsrc, WT);
        conv_mfma16_kernel<<<dim3(OH, N_IMG), dim3(256), 0, stream>>>(In, WT, Out);
    } else {
        const int total = N_IMG * COUT * OH * OW;
        conv_naive_kernel<<<dim3((total + 255) / 256), dim3(256), 0, stream>>>(In, Wsrc, Out);
    }
}